// Round 12
// baseline (345.139 us; speedup 1.0000x reference)
//
#include <hip/hip_runtime.h>

#define BATCH 131072
#define NS    300
#define H     100
#define BLK   64                  /* 1 wave per block: no barriers, max phase diversity */
#define EPB   32                  /* 16 quads x 2 elements */
#define NBLK  (BATCH / EPB)       /* 4096 blocks -> 16 blocks/CU = 4 waves/SIMD */
#define NQ4   (EPB * NS / 4)      /* 2400 float4 outputs per block */

#define REP25(M) M(0) M(1) M(2) M(3) M(4) M(5) M(6) M(7) M(8) M(9) M(10) M(11) \
  M(12) M(13) M(14) M(15) M(16) M(17) M(18) M(19) M(20) M(21) M(22) M(23) M(24)

__device__ __forceinline__ float qswap1(float x) {   /* quad_perm [1,0,3,2] */
    return __int_as_float(__builtin_amdgcn_mov_dpp(__float_as_int(x), 0xB1, 0xF, 0xF, true));
}
__device__ __forceinline__ float qswap2(float x) {   /* quad_perm [2,3,0,1] */
    return __int_as_float(__builtin_amdgcn_mov_dpp(__float_as_int(x), 0x4E, 0xF, 0xF, true));
}

/* pack W2 + heads + b2 into [j][q][32] float rows:
   [0..24] = W2[j][q*25 .. +25], [25..27] = 0,
   [28] = Ww0[q][j], [29] = Wwp[q][j], [30] = Wg[q][j], [31] = b2[j].
   One contiguous 128B row per (j,q) -> 8 float4 loads in the j-loop. */
__global__ void prep_pack(const float* __restrict__ W2,  const float* __restrict__ b2,
                          const float* __restrict__ Ww0, const float* __restrict__ Wwp,
                          const float* __restrict__ Wg,  float* __restrict__ W2C) {
    const int i = blockIdx.x * 256 + threadIdx.x;
    if (i < 12800) {
        const int r = i >> 5, kk = i & 31;
        const int j = r >> 2, q = r & 3;
        float v;
        if      (kk < 25)  v = W2[j * H + q * 25 + kk];
        else if (kk < 28)  v = 0.f;
        else if (kk == 28) v = Ww0[q * H + j];
        else if (kk == 29) v = Wwp[q * H + j];
        else if (kk == 30) v = Wg [q * H + j];
        else               v = b2[j];
        W2C[i] = v;
    }
}

__global__ __launch_bounds__(BLK, 4)   /* 4 waves/EU min -> VGPR cap 128, live set ~100 */
void lorentz_fused(const float* __restrict__ G,  const float* __restrict__ W1,
                   const float* __restrict__ b1, const float* __restrict__ W2C,
                   float* __restrict__ out)
{
    __shared__ float sP[3 * EPB * 4];   /* 1536 B: P0|P1|P2 tables, [el*4+q] each */

    const int l  = threadIdx.x;         /* 0..63 */
    const int q  = l & 3;               /* k-chunk / oscillator owner */
    const int pr = l >> 2;              /* element pair 0..15 */
    const int e0 = blockIdx.x * EPB + pr * 2;

    /* ---- inputs for 2 elements (quad-mates read same rows -> broadcast) ---- */
    const float4* gp = (const float4*)(G + (size_t)e0 * 8);
    const float4 ga0 = gp[0], gb0 = gp[1];
    const float4 ga1 = gp[2], gb1 = gp[3];

    /* ---- layer 1: lane computes h1[q*25 .. q*25+24] for 2 elements.
       W1/b1 from global (3.6 KB, L1-resident, 4-distinct-addr broadcast). ---- */
#define H1DECL(i) float h1a_##i, h1b_##i;
    REP25(H1DECL)
#undef H1DECL
#define L1E(dst, ga, gb)                                                        \
        { float s0 = fmaf(ga.x, ra.x, bb);  float s1 = ga.y * ra.y;             \
          s0 = fmaf(ga.z, ra.z, s0);  s1 = fmaf(ga.w, ra.w, s1);                \
          s0 = fmaf(gb.x, rb.x, s0);  s1 = fmaf(gb.y, rb.y, s1);                \
          s0 = fmaf(gb.z, rb.z, s0);  s1 = fmaf(gb.w, rb.w, s1);                \
          dst = fmaxf(s0 + s1, 0.f); }
#define L1(i) { const float4* r = (const float4*)(W1 + (q * 25 + (i)) * 8);     \
        const float4 ra = r[0], rb = r[1];                                      \
        const float bb = b1[q * 25 + (i)];                                      \
        L1E(h1a_##i, ga0, gb0)  L1E(h1b_##i, ga1, gb1) }
    REP25(L1)
#undef L1

    /* ---- layer 2 + heads: per j, one 128B packed row from global (VMEM pipe,
       L1-cached); 25-fma partial dot x2 elements; DPP quad butterfly; heads. ---- */
    float aw0a = 0.f, awpa = 0.f, agga = 0.f;
    float aw0b = 0.f, awpb = 0.f, aggb = 0.f;

#pragma unroll 1
    for (int j = 0; j < H; ++j) {
        const float4* wr = (const float4*)(W2C + (size_t)((j << 2) + q) * 32);
        const float4 c0 = wr[0], c1 = wr[1], c2 = wr[2], c3 = wr[3],
                     c4 = wr[4], c5 = wr[5], c6 = wr[6], hv = wr[7];

        float pa = 0.f, pb = 0.f;
#define CH1(w, i) pa = fmaf(h1a_##i, w, pa); pb = fmaf(h1b_##i, w, pb);
#define CH(t, i0, i1, i2, i3)                                                   \
        CH1(c##t.x, i0) CH1(c##t.y, i1) CH1(c##t.z, i2) CH1(c##t.w, i3)
        CH(0, 0, 1, 2, 3)     CH(1, 4, 5, 6, 7)     CH(2, 8, 9, 10, 11)
        CH(3, 12, 13, 14, 15) CH(4, 16, 17, 18, 19) CH(5, 20, 21, 22, 23)
        CH1(c6.x, 24)
#undef CH
#undef CH1
        float sa = pa + qswap1(pa); sa += qswap2(sa);
        float sb = pb + qswap1(pb); sb += qswap2(sb);
        const float h2a = fmaxf(sa + hv.w, 0.f);   /* hv.w = b2[j] */
        const float h2b = fmaxf(sb + hv.w, 0.f);

        aw0a = fmaf(h2a, hv.x, aw0a); awpa = fmaf(h2a, hv.y, awpa); agga = fmaf(h2a, hv.z, agga);
        aw0b = fmaf(h2b, hv.x, aw0b); awpb = fmaf(h2b, hv.y, awpb); aggb = fmaf(h2b, hv.z, aggb);
    }

    /* ---- derived params -> tiny LDS table (single wave: barrier is cheap) ---- */
    {
#define EMIT(aw, ap, ag, e)                                                     \
        { const float w0 = fmaxf(aw, 0.f), wp = fmaxf(ap, 0.f), gg = fmaxf(ag, 0.f); \
          const int ix = (pr * 2 + (e)) * 4 + q;                                \
          sP[ix] = w0 * w0;  sP[128 + ix] = gg * gg;  sP[256 + ix] = wp * wp * gg; }
        EMIT(aw0a, awpa, agga, 0)
        EMIT(aw0b, awpb, aggb, 1)
#undef EMIT
    }
    __syncthreads();

    /* ---- spectrum: block's contiguous 32*300-float region, float4 stores.
       2400 quads = 37 full wave-iters + half-wave tail. sP reads broadcast. ---- */
    const float4* sP0 = (const float4*)sP;
    const float4* sP1 = (const float4*)(sP + 128);
    const float4* sP2 = (const float4*)(sP + 256);
    float4* out4 = (float4*)out;
    const size_t base4 = (size_t)blockIdx.x * NQ4;

#define SPEC(idx4)                                                              \
    {   const int e  = (idx4) / 75;                                             \
        const int k4 = (idx4) - e * 75;                                         \
        const float4 P0 = sP0[e], P1 = sP1[e], P2 = sP2[e];                     \
        const float kb = (float)(k4 << 2);                                      \
        float4 r; float* rp = (float*)&r;                                       \
        _Pragma("unroll")                                                       \
        for (int i = 0; i < 4; ++i) {                                           \
            const float w_  = 0.5f + (kb + (float)i) * 0.015f;                  \
            const float wsq = w_ * w_;                                          \
            const float t0 = P0.x - wsq, t1 = P0.y - wsq,                       \
                        t2 = P0.z - wsq, t3 = P0.w - wsq;                       \
            const float d0 = fmaf(t0, t0, wsq * P1.x);                          \
            const float d1 = fmaf(t1, t1, wsq * P1.y);                          \
            const float d2 = fmaf(t2, t2, wsq * P1.z);                          \
            const float d3 = fmaf(t3, t3, wsq * P1.w);                          \
            const float d01 = d0 * d1, d23 = d2 * d3;                           \
            const float D   = d01 * d23;                                        \
            const float n01 = fmaf(P2.y, d0, P2.x * d1);                        \
            const float n23 = fmaf(P2.w, d2, P2.z * d3);                        \
            const float N   = fmaf(n01, d23, n23 * d01);                        \
            rp[i] = w_ * (N * __builtin_amdgcn_rcpf(D));                        \
        }                                                                       \
        out4[base4 + (idx4)] = r; }

    for (int it = 0; it < NQ4 / BLK; ++it) {        /* 37 iterations */
        const int idx4 = it * BLK + l;
        SPEC(idx4)
    }
    if (l < NQ4 - (NQ4 / BLK) * BLK) {              /* tail: 32 quads */
        const int idx4 = (NQ4 / BLK) * BLK + l;
        SPEC(idx4)
    }
#undef SPEC
}

extern "C" void kernel_launch(void* const* d_in, const int* in_sizes, int n_in,
                              void* d_out, int out_size, void* d_ws, size_t ws_size,
                              hipStream_t stream) {
    const float* G   = (const float*)d_in[0];
    const float* W1  = (const float*)d_in[1];
    const float* b1  = (const float*)d_in[2];
    const float* W2  = (const float*)d_in[3];
    const float* b2  = (const float*)d_in[4];
    const float* Ww0 = (const float*)d_in[5];
    const float* Wwp = (const float*)d_in[6];
    const float* Wg  = (const float*)d_in[7];
    float* out = (float*)d_out;
    float* W2C = (float*)d_ws;                 /* 51200 B scratch */

    prep_pack<<<50, 256, 0, stream>>>(W2, b2, Ww0, Wwp, Wg, W2C);
    lorentz_fused<<<NBLK, BLK, 0, stream>>>(G, W1, b1, W2C, out);
}

// Round 13
// 100.630 us; speedup vs baseline: 3.4298x; 3.4298x over previous
//
#include <hip/hip_runtime.h>

#define BATCH 131072
#define NS    300
#define H     100
#define BLK   256
#define EPB   64                  /* 2048 blocks -> 8 generations/CU, phase overlap */
#define NBLK  (BATCH / EPB)
#define NQ4   (EPB * NS / 4)      /* 4800 quads per block */
#define H2STR 112                 /* h2 slab row stride (f32) */
#define LOOFF 14336               /* ushort offset of lo plane (28 frags * 64 * 8) */

typedef __attribute__((ext_vector_type(8))) short bf16x8;
typedef __attribute__((ext_vector_type(4))) float f32x4;

__device__ __forceinline__ unsigned short f2bf(float f) {
    unsigned int u = __float_as_uint(f);
    return (unsigned short)((u + 0x7fffu + ((u >> 16) & 1u)) >> 16);
}
__device__ __forceinline__ float bf2f(unsigned short h) {
    return __uint_as_float(((unsigned int)h) << 16);
}

/* B-frags of W2^T, split-bf16, zero-padded 128x112 (verbatim R11, HW-verified). */
__global__ void prep_w2(const float* __restrict__ W2, unsigned short* __restrict__ wsb) {
    const int fi   = blockIdx.x * 4 + (threadIdx.x >> 6);
    const int lane = threadIdx.x & 63;
    const int s = fi / 7, t = fi % 7;
    const int n  = t * 16 + (lane & 15);
    const int k0 = s * 32 + ((lane >> 4) << 3);
    unsigned short* hi = wsb + ((size_t)fi * 64 + lane) * 8;
#pragma unroll
    for (int i = 0; i < 8; ++i) {
        const int k = k0 + i;
        const float v = (k < H && n < H) ? W2[n * H + k] : 0.f;
        const unsigned short h = f2bf(v);
        hi[i]         = h;
        hi[LOOFF + i] = f2bf(v - bf2f(h));
    }
}

/* HdT[12][112] (rows 0-3 Ww0, 4-7 Wwp, 8-11 Wg; j>=100 zero) + b2p[112]. */
__global__ void prep_small(const float* __restrict__ Ww0, const float* __restrict__ Wwp,
                           const float* __restrict__ Wg,  const float* __restrict__ b2,
                           float* __restrict__ hdt, float* __restrict__ b2p) {
    const int i = blockIdx.x * 256 + threadIdx.x;
    if (i < 12 * 112) {
        const int c = i / 112, j = i % 112;
        const float* src = (c < 4) ? Ww0 : (c < 8) ? Wwp : Wg;
        hdt[i] = (j < H) ? src[(c & 3) * H + j] : 0.f;
    }
    if (i < 112) b2p[i] = (i < H) ? b2[i] : 0.f;
}

__global__ __launch_bounds__(BLK)
void lorentz_fused(const float* __restrict__ G,   const float* __restrict__ W1,
                   const float* __restrict__ b1,  const unsigned short* __restrict__ wsb,
                   const float* __restrict__ hdt, const float* __restrict__ b2p,
                   float* __restrict__ out)
{
    __shared__ __align__(16) float h2buf[4][16][H2STR];  /* 28672 B, per-wave slabs */
    __shared__ __align__(16) float sPP[EPB * 12];        /*  3072 B params */

    const int tid  = threadIdx.x;
    const int w    = tid >> 6, lane = tid & 63, ln = lane & 15, gr = lane >> 4;
    const int e0   = blockIdx.x * EPB + w * 16;

    /* ---- this lane's batch row (A-operand row = e0 + ln) ---- */
    const float4* gp = (const float4*)(G + (size_t)(e0 + ln) * 8);
    const float4 gA = gp[0], gB = gp[1];

    f32x4 acc[7];
#pragma unroll
    for (int t = 0; t < 7; ++t) acc[t] = (f32x4){0.f, 0.f, 0.f, 0.f};

    const bf16x8* Bf = (const bf16x8*)wsb;

    /* ---- L1 + L2 fused: per s-chunk, compute 8 h1 values directly as the
       A-frag (k = s*32+gr*8+i; same bijection as prep_w2 -> any HW k-perm
       cancels), split-bf16 pack, then 21 MFMAs. h1 never stored.
       k>=100: clamp W1 row (finite garbage); B-frag is zero there -> exact. */
#pragma unroll
    for (int s = 0; s < 4; ++s) {
        bf16x8 ahi, alo;
#pragma unroll
        for (int i = 0; i < 8; ++i) {
            const int k  = s * 32 + gr * 8 + i;
            const int kc = (k < H) ? k : (H - 1);
            const float4 ra = ((const float4*)(W1 + kc * 8))[0];
            const float4 rb = ((const float4*)(W1 + kc * 8))[1];
            float s0 = fmaf(gA.x, ra.x, b1[kc]);
            float s1 = gA.y * ra.y;
            s0 = fmaf(gA.z, ra.z, s0);  s1 = fmaf(gA.w, ra.w, s1);
            s0 = fmaf(gB.x, rb.x, s0);  s1 = fmaf(gB.y, rb.y, s1);
            s0 = fmaf(gB.z, rb.z, s0);  s1 = fmaf(gB.w, rb.w, s1);
            const float h = fmaxf(s0 + s1, 0.f);
            const unsigned short hh = f2bf(h);
            ahi[i] = (short)hh;
            alo[i] = (short)f2bf(h - bf2f(hh));
        }
#pragma unroll
        for (int t = 0; t < 7; ++t) {
            const bf16x8 bh = Bf[(s * 7 + t) * 64 + lane];
            const bf16x8 bl = Bf[1792 + (s * 7 + t) * 64 + lane];
            acc[t] = __builtin_amdgcn_mfma_f32_16x16x32_bf16(ahi, bh, acc[t], 0, 0, 0);
            acc[t] = __builtin_amdgcn_mfma_f32_16x16x32_bf16(ahi, bl, acc[t], 0, 0, 0);
            acc[t] = __builtin_amdgcn_mfma_f32_16x16x32_bf16(alo, bh, acc[t], 0, 0, 0);
        }
    }

    /* ---- h2 = relu(acc + b2) -> per-wave slab (C/D layout: row gr*4+r, col t*16+ln) ---- */
#pragma unroll
    for (int t = 0; t < 7; ++t) {
        const float b2v = b2p[t * 16 + ln];
#pragma unroll
        for (int r = 0; r < 4; ++r)
            h2buf[w][gr * 4 + r][t * 16 + ln] = fmaxf(acc[t][r] + b2v, 0.f);
    }
    __syncthreads();

    /* ---- heads: lane (row = lane>>2, q = lane&3) does three 112-dots; no cross-lane ---- */
    {
        const int row = lane >> 2, q = lane & 3;
        const float4* h4 = (const float4*)&h2buf[w][row][0];
        const float4* d0 = (const float4*)(hdt + q * 112);        /* Ww0[q] */
        const float4* d1 = (const float4*)(hdt + (4 + q) * 112);  /* Wwp[q] */
        const float4* d2 = (const float4*)(hdt + (8 + q) * 112);  /* Wg [q] */
        float s0 = 0.f, s1 = 0.f, s2 = 0.f;
#pragma unroll
        for (int k4 = 0; k4 < 28; ++k4) {
            const float4 hv = h4[k4];
            const float4 a = d0[k4], b = d1[k4], c = d2[k4];
            s0 = fmaf(hv.x, a.x, s0); s1 = fmaf(hv.x, b.x, s1); s2 = fmaf(hv.x, c.x, s2);
            s0 = fmaf(hv.y, a.y, s0); s1 = fmaf(hv.y, b.y, s1); s2 = fmaf(hv.y, c.y, s2);
            s0 = fmaf(hv.z, a.z, s0); s1 = fmaf(hv.z, b.z, s1); s2 = fmaf(hv.z, c.z, s2);
            s0 = fmaf(hv.w, a.w, s0); s1 = fmaf(hv.w, b.w, s1); s2 = fmaf(hv.w, c.w, s2);
        }
        const float w0 = fmaxf(s0, 0.f), wp = fmaxf(s1, 0.f), gg = fmaxf(s2, 0.f);
        const int el = w * 16 + row;
        sPP[el * 12 + q]     = w0 * w0;        /* P0 */
        sPP[el * 12 + 4 + q] = gg * gg;        /* P1 */
        sPP[el * 12 + 8 + q] = wp * wp * gg;   /* P2 */
    }
    __syncthreads();

    /* ---- spectrum: block's contiguous 64*300-float region (R6/R10-proven) ---- */
    float4* out4 = (float4*)out;
    const size_t base4 = (size_t)blockIdx.x * NQ4;

#define SPEC(idx4)                                                              \
    {   const int e  = (idx4) / 75;                                             \
        const int k4 = (idx4) - e * 75;                                         \
        const float4 P0 = ((const float4*)(sPP + e * 12))[0];                   \
        const float4 P1 = ((const float4*)(sPP + e * 12))[1];                   \
        const float4 P2 = ((const float4*)(sPP + e * 12))[2];                   \
        const float kb = (float)(k4 << 2);                                      \
        float4 r; float* rp = (float*)&r;                                       \
        _Pragma("unroll")                                                       \
        for (int i = 0; i < 4; ++i) {                                           \
            const float w_  = 0.5f + (kb + (float)i) * 0.015f;                  \
            const float wsq = w_ * w_;                                          \
            const float t0 = P0.x - wsq, t1 = P0.y - wsq,                       \
                        t2 = P0.z - wsq, t3 = P0.w - wsq;                       \
            const float d0 = fmaf(t0, t0, wsq * P1.x);                          \
            const float d1 = fmaf(t1, t1, wsq * P1.y);                          \
            const float d2 = fmaf(t2, t2, wsq * P1.z);                          \
            const float d3 = fmaf(t3, t3, wsq * P1.w);                          \
            const float d01 = d0 * d1, d23 = d2 * d3;                           \
            const float D   = d01 * d23;                                        \
            const float n01 = fmaf(P2.y, d0, P2.x * d1);                        \
            const float n23 = fmaf(P2.w, d2, P2.z * d3);                        \
            const float N   = fmaf(n01, d23, n23 * d01);                        \
            rp[i] = w_ * (N * __builtin_amdgcn_rcpf(D));                        \
        }                                                                       \
        out4[base4 + (idx4)] = r; }

    for (int it = 0; it < NQ4 / BLK; ++it) {        /* 18 iterations */
        const int idx4 = it * BLK + tid;
        SPEC(idx4)
    }
    if (tid < NQ4 - (NQ4 / BLK) * BLK) {            /* tail: 192 quads */
        const int idx4 = (NQ4 / BLK) * BLK + tid;
        SPEC(idx4)
    }
#undef SPEC
}

extern "C" void kernel_launch(void* const* d_in, const int* in_sizes, int n_in,
                              void* d_out, int out_size, void* d_ws, size_t ws_size,
                              hipStream_t stream) {
    const float* G   = (const float*)d_in[0];
    const float* W1  = (const float*)d_in[1];
    const float* b1  = (const float*)d_in[2];
    const float* W2  = (const float*)d_in[3];
    const float* b2  = (const float*)d_in[4];
    const float* Ww0 = (const float*)d_in[5];
    const float* Wwp = (const float*)d_in[6];
    const float* Wg  = (const float*)d_in[7];
    float* out = (float*)d_out;

    unsigned short* wsb = (unsigned short*)d_ws;            /* 57344 B */
    float* hdt = (float*)((char*)d_ws + 57344);             /*  5376 B */
    float* b2p = (float*)((char*)d_ws + 57344 + 5376);      /*   448 B */

    prep_w2<<<7, 256, 0, stream>>>(W2, wsb);
    prep_small<<<6, 256, 0, stream>>>(Ww0, Wwp, Wg, b2, hdt, b2p);
    lorentz_fused<<<NBLK, BLK, 0, stream>>>(G, W1, b1, wsb, hdt, b2p, out);
}